// Round 1
// baseline (119.218 us; speedup 1.0000x reference)
//
#include <hip/hip_runtime.h>
#include <stdint.h>

#define NI 128
#define NA 285
#define ND 183
#define NT 384
#define RAYS (NA * ND)        // 52155
#define PITCH 133             // dwords per packed row
#define PROWS 132
#define PLDS (PROWS * PITCH + 1)  // 17557 dwords = 70,228 B -> 2 blocks/CU
#define TPB 832               // 13 waves
#define WAVES 13
#define NBLK 64               // blocks per image -> grid 512 = exactly 2/CU
#define SLOTS (NBLK * WAVES)  // 832 wave slots per image
#define NGRP 12               // 12 det-groups of 16 per angle (183 dets + 9 pad)
#define NTASKS (NA * NGRP)    // 3420 wave-tasks per image
#define ROUNDS 5              // 832*5 = 4160 slots >= 3420

typedef __fp16 half2v __attribute__((ext_vector_type(2)));

constexpr float PI_F  = 3.14159265358979323846f;
constexpr float RHO_F = 28.284271247461902f;   // 20*sqrt(2)
constexpr float DX_F  = 0.3125f;
constexpr float DT_F  = 2.0f * RHO_F / NT;

// R16: detector-major restructure. A wave = (angle, 16 consecutive dets) x
// 4-way (h,p) t-split; each lane reads ONLY its own ray: 1 ds_read2_b32 per
// sample instead of 4 mirror reads. The old 4-ray symmetry amortized VALU
// (hidden) at the cost of randomizing LDS addresses (the ~3x bank-conflict
// factor). Here lane addresses stride regularly along the detector axis
// (~0.989*(-133*sin + cos) dwords/lane) -> near-conflict-free for all but
// ~2% of angles. Per-ray arithmetic & accumulation order identical to the
// old base-ray path -> absmax unchanged.
// Column 1 / row-pair semantics of the zero ring unchanged (R13's bug):
// clamp [0.5,130.49] guarantees all out-of-support reads land on zero
// rows/cols (row 0 pair is (pad0,pad1)=both zero; f0=130 pair is zeros;
// cols {0,1} and {130,131} zero in every row).
__global__ __launch_bounds__(TPB) void radon_fwd(const float* __restrict__ x,
                                                 float* __restrict__ out) {
    __shared__ __align__(16) unsigned int P[PLDS];
    const int tid = threadIdx.x;
    const int img = blockIdx.x >> 6;
    const int blk = blockIdx.x & 63;

    // Ring-only zero fill (disjoint from pack writes -> single barrier).
    // rows 0,130,131 full; rows 1..129 cols {0,1,130,131,132}.
    for (int i = tid; i < 1432; i += TPB) {
        int r, c;
        if (i < 399) { r = (i < 133) ? 0 : (i < 266 ? 130 : 131);
                       c = i - ((i < 133) ? 0 : (i < 266 ? 133 : 266)); }
        else { int k = i - 399; r = 1 + (k >> 3);
               const int map[8] = {0, 1, 130, 131, 132, 0, 1, 130};
               c = map[k & 7]; }
        P[r * PITCH + c] = 0;
    }
    if (tid == 0) P[PLDS - 1] = 0;

    // Vertical-pair pack: P[pr*133+pc] = half2(pad[pr][pc], pad[pr+1][pc]),
    // pad = image with 2-cell zero ring. Only pc in [2,129] nonzero.
    const float4* src = (const float4*)(x + img * NI * NI);
    for (int i = tid; i < 129 * 32; i += TPB) {
        int pr  = 1 + (i >> 5);
        int g   = i & 31;
        int rlo = pr - 2;
        int rhi = pr - 1;
        float4 vlo = (rlo >= 0)   ? src[rlo * 32 + g] : make_float4(0, 0, 0, 0);
        float4 vhi = (rhi <= 127) ? src[rhi * 32 + g] : make_float4(0, 0, 0, 0);
        int base = pr * PITCH + 2 + g * 4;
        P[base + 0] = __builtin_bit_cast(unsigned int, __builtin_amdgcn_cvt_pkrtz(vlo.x, vhi.x));
        P[base + 1] = __builtin_bit_cast(unsigned int, __builtin_amdgcn_cvt_pkrtz(vlo.y, vhi.y));
        P[base + 2] = __builtin_bit_cast(unsigned int, __builtin_amdgcn_cvt_pkrtz(vlo.z, vhi.z));
        P[base + 3] = __builtin_bit_cast(unsigned int, __builtin_amdgcn_cvt_pkrtz(vlo.w, vhi.w));
    }
    __syncthreads();

    const int w_id = tid >> 6;
    const int lane = tid & 63;
    const int sidx = blk * WAVES + w_id;        // 0..831
    // x181 mod 832 permutation (gcd=1): scatters the 92 five-task waves
    // across blocks AND gives each wave 5 angle-diverse tasks (balances
    // block durations).
    const int perm = (sidx * 181) % SLOTS;
    const int dloc = lane & 15;                 // det within group
    const int q    = lane >> 4;                 // (h,p) t-split
    const int h    = q >> 1;
    const int pp   = q & 1;
    const float sgn = h ? 1.0f : -1.0f;

    const char* Pb = (const char*)P;
    const float inv_dx = 1.0f / DX_F;
    const float inv_dt = 1.0f / DT_F;
    const float t0v    = -RHO_F + 0.5f * DT_F;
    const float LIM    = 20.157f;   // bilinear support |p| <= 20 + DX/2 (+ fp margin)

    for (int r = 0; r < ROUNDS; ++r) {
        const int task = r * SLOTS + perm;      // wave-uniform
        if (task >= NTASKS) break;              // only possible at r==4
        const int a = task / NGRP;
        const int g = task - a * NGRP;
        const int d = g * 16 + dloc;
        const bool valid = (d < ND);

        const float ang = ((float)a + 0.5f) * (PI_F / (float)NA);
        float sn, cs;
        sincosf(ang, &sn, &cs);
        const float s = -RHO_F + ((float)d + 0.5f) * (2.0f * RHO_F / (float)ND);

        const float e0 = -s * sn;
        const float e1 =  s * cs;
        const float c0p = (e0 + t0v * cs + 20.0f) * inv_dx + 1.5f;  // padded
        const float c1p = (e1 + t0v * sn + 20.0f) * inv_dx + 1.5f;
        const float st0 = DT_F * cs * inv_dx;
        const float st1 = DT_F * sn * inv_dx;

        // Clip to bilinear support.
        const float inv_cs = 1.0f / cs;
        const float inv_sn = 1.0f / sn;
        float ta = (-LIM - e0) * inv_cs, tb = (LIM - e0) * inv_cs;
        float tc = (-LIM - e1) * inv_sn, td = (LIM - e1) * inv_sn;
        float tlo = fmaxf(fminf(ta, tb), fminf(tc, td));
        float thi = fminf(fmaxf(ta, tb), fmaxf(tc, td));
        float fk0 = fminf(fmaxf(ceilf((tlo - t0v) * inv_dt), 0.0f), 384.0f);
        float fk1 = fminf(fmaxf(floorf((thi - t0v) * inv_dt), -1.0f), 383.0f);
        const int kmin = (int)fk0;
        const int kmax = (int)fk1;
        const int kmid = (kmin + kmax + 1) >> 1;

        // Half lengths; lane runs ceil(max/2) steps at stride 2 (parity split).
        int ldown = kmid - kmin;
        int lup   = kmax - kmid + 1;
        int mylen = (max(max(ldown, lup), 0) + 1) >> 1;
        if (!valid) mylen = 0;

        // Wave envelope (16 adjacent dets x 4 t-phases -> tight).
        int Lw = mylen;
        #pragma unroll
        for (int off = 32; off >= 1; off >>= 1)
            Lw = max(Lw, __shfl_xor(Lw, off, 64));

        const float st0s = st0 * (2.0f * sgn);
        const float st1s = st1 * (2.0f * sgn);
        const int   ks   = h ? (kmid + pp) : (kmid - 1 - pp);
        float i0 = fmaf((float)ks, st0, c0p);
        float i1 = fmaf((float)ks, st1, c1p);
        float acc = 0.0f;

        #pragma unroll 4
        for (int m = 0; m < Lw; ++m) {
            // Clamp [0.5,130.49]: identity in-support; overrun -> zero
            // rows/cols.
            float q0 = fminf(fmaxf(i0, 0.5f), 130.49f);
            float q1 = fminf(fmaxf(i1, 0.5f), 130.49f);
            i0 += st0s;
            i1 += st1s;
            float f0 = floorf(q0);
            float f1 = floorf(q1);
            float a0 = q0 - f0;
            float a1 = q1 - f1;
            // Byte offset, float-domain (exact: max 130*532+520 < 2^24).
            int bidx = (int)fmaf(f0, 532.0f, 4.0f * f1);
            unsigned int u0 = *(const unsigned int*)(Pb + bidx);
            unsigned int u1 = *(const unsigned int*)(Pb + bidx + 4);
            half2v w  = __builtin_amdgcn_cvt_pkrtz(1.0f - a0, a0);
            half2v b1 = __builtin_amdgcn_cvt_pkrtz(a1, a1);
            half2v wB = w * b1;                  // v_pk_mul_f16
            half2v wA = w - wB;                  // == w*(1-a1)
            acc = __builtin_amdgcn_fdot2(__builtin_bit_cast(half2v, u0), wA, acc, false);
            acc = __builtin_amdgcn_fdot2(__builtin_bit_cast(half2v, u1), wB, acc, false);
        }

        // Combine the 4 t-phase lanes of this ray (same d, a).
        acc += __shfl_xor(acc, 16, 64);
        acc += __shfl_xor(acc, 32, 64);
        if (valid && q == 0)
            out[img * RAYS + a * ND + d] = acc * (DT_F / 12.0f);
    }
}

extern "C" void kernel_launch(void* const* d_in, const int* in_sizes, int n_in,
                              void* d_out, int out_size, void* d_ws, size_t ws_size,
                              hipStream_t stream) {
    const float* x = (const float*)d_in[0];
    float* out = (float*)d_out;
    const int B = in_sizes[0] / (NI * NI);   // 8
    dim3 grid(B * NBLK);
    radon_fwd<<<grid, TPB, 0, stream>>>(x, out);
}

// Round 3
// 94.714 us; speedup vs baseline: 1.2587x; 1.2587x over previous
//
#include <hip/hip_runtime.h>
#include <stdint.h>

#define NI 128
#define NA 285
#define ND 183
#define NT 384
#define RAYS (NA * ND)        // 52155
#define PITCH 133             // dwords per packed row
#define PROWS 132
#define PLDS (PROWS * PITCH + 1)  // 17557 dwords = 70,228 B -> 2 blocks/CU
#define TPB 832               // 13 waves
#define WAVES 13
#define NBLK 64               // blocks per image -> grid 512 = exactly 2/CU
#define SLOTS (NBLK * WAVES)  // 832 wave slots per image
#define NAP 143               // angle-pair index ap (ap=142 self-pair)
#define NGRPJ 6               // 6 groups of 16 det-pair indices (92 j + 4 pad)
#define NTASKS (NAP * NGRPJ)  // 858 wave-tasks per image
#define ROUNDS 2              // 832*2 = 1664 >= 858; 26 waves run 2 tasks
#define IDXM 17420            // 130*133+130: det-mirror idx' = IDXM - idx
#define BIDXM (IDXM * 4)      // byte-domain mirror constant

typedef __fp16 half2v __attribute__((ext_vector_type(2)));

constexpr float PI_F  = 3.14159265358979323846f;
constexpr float RHO_F = 28.284271247461902f;   // 20*sqrt(2)
constexpr float DX_F  = 0.3125f;
constexpr float DT_F  = 2.0f * RHO_F / NT;

// R17 (resubmit after container failure): detector-major lanes + 4-ray
// symmetry inner loop (compose R15+R16).
// R16's counters showed the 4-ray removal made the kernel VALU-bound
// (VALUBusy 66%) while proving det-major lane strides are conflict-benign
// (6.2M conflict cycles = 13%). Here: wave = (ap, 16 consecutive j) x 4
// (h,p) t-phases; ONE position/weight computation per lane-iter feeds the
// 4 mirror rays (base, det-mirror, angle-mirror, both) -> per-sample VALU
// back to ~0.12 issue-slots. Each of the 4 LDS read classes is a regular
// 16-lane stride (~0.989*(-133*sin+cos) dwords/det); mirrors of regular
// strides stay regular -> conflicts stay benign (unlike the old
// angle-major lanes whose 64 scattered addresses cost ~2x DS).
// Inner arithmetic verbatim from the proven 82us kernel -> absmax equal.
// Column 1 MUST stay zero (pad col 1 = image col -1): mirror reads at
// col' = 130-f1 hit it for in-support boundary samples (R13's bug).
__global__ __launch_bounds__(TPB) void radon_fwd(const float* __restrict__ x,
                                                 float* __restrict__ out) {
    __shared__ __align__(16) unsigned int P[PLDS];
    const int tid = threadIdx.x;
    const int img = blockIdx.x >> 6;
    const int blk = blockIdx.x & 63;

    // Ring-only zero fill (disjoint from pack writes -> single barrier).
    // rows 0,130,131 full; rows 1..129 cols {0,1,130,131,132}.
    for (int i = tid; i < 1432; i += TPB) {
        int r, c;
        if (i < 399) { r = (i < 133) ? 0 : (i < 266 ? 130 : 131);
                       c = i - ((i < 133) ? 0 : (i < 266 ? 133 : 266)); }
        else { int k = i - 399; r = 1 + (k >> 3);
               const int map[8] = {0, 1, 130, 131, 132, 0, 1, 130};
               c = map[k & 7]; }
        P[r * PITCH + c] = 0;
    }
    if (tid == 0) P[PLDS - 1] = 0;

    // Vertical-pair pack: P[pr*133+pc] = half2(pad[pr][pc], pad[pr+1][pc]),
    // pad = image with 2-cell zero ring. Only pc in [2,129] nonzero.
    const float4* src = (const float4*)(x + img * NI * NI);
    for (int i = tid; i < 129 * 32; i += TPB) {
        int pr  = 1 + (i >> 5);
        int g   = i & 31;
        int rlo = pr - 2;
        int rhi = pr - 1;
        float4 vlo = (rlo >= 0)   ? src[rlo * 32 + g] : make_float4(0, 0, 0, 0);
        float4 vhi = (rhi <= 127) ? src[rhi * 32 + g] : make_float4(0, 0, 0, 0);
        int base = pr * PITCH + 2 + g * 4;
        P[base + 0] = __builtin_bit_cast(unsigned int, __builtin_amdgcn_cvt_pkrtz(vlo.x, vhi.x));
        P[base + 1] = __builtin_bit_cast(unsigned int, __builtin_amdgcn_cvt_pkrtz(vlo.y, vhi.y));
        P[base + 2] = __builtin_bit_cast(unsigned int, __builtin_amdgcn_cvt_pkrtz(vlo.z, vhi.z));
        P[base + 3] = __builtin_bit_cast(unsigned int, __builtin_amdgcn_cvt_pkrtz(vlo.w, vhi.w));
    }
    __syncthreads();

    const int w_id = tid >> 6;
    const int lane = tid & 63;
    const int sidx = blk * WAVES + w_id;        // 0..831
    // x181 mod 832 permutation (gcd=1): scatters tasks across blocks.
    // The 26 doubled waves (perm<26) pair ap~0 (r0) with ap~142 (r1) —
    // both are the SHORT chord classes (274 samples vs 387 max) -> mild tail.
    const int perm = (sidx * 181) % SLOTS;
    const int dloc = lane & 15;                 // det-pair within group
    const int q    = lane >> 4;                 // (h,p) t-split
    const int h    = q >> 1;
    const int pp   = q & 1;
    const float sgn = h ? 1.0f : -1.0f;

    const char* Pb = (const char*)P;
    const float inv_dx = 1.0f / DX_F;
    const float inv_dt = 1.0f / DT_F;
    const float t0v    = -RHO_F + 0.5f * DT_F;
    const float LIM    = 20.157f;   // bilinear support |p| <= 20 + DX/2 (+ fp margin)

    for (int r = 0; r < ROUNDS; ++r) {
        const int task = r * SLOTS + perm;      // wave-uniform
        if (task >= NTASKS) break;              // only possible at r==1
        const int ap = task / NGRPJ;            // 0..142
        const int g  = task - ap * NGRPJ;       // 0..5
        const int j  = g * 16 + dloc;           // det-pair index, valid < 92
        const bool valid = (j < 92);

        const float ang = ((float)ap + 0.5f) * (PI_F / (float)NA);
        float sn, cs;
        sincosf(ang, &sn, &cs);
        const float s = -RHO_F + ((float)j + 0.5f) * (2.0f * RHO_F / (float)ND);

        const float e0 = -s * sn;
        const float e1 =  s * cs;
        const float c0p = (e0 + t0v * cs + 20.0f) * inv_dx + 1.5f;  // padded
        const float c1p = (e1 + t0v * sn + 20.0f) * inv_dx + 1.5f;
        const float st0 = DT_F * cs * inv_dx;
        const float st1 = DT_F * sn * inv_dx;

        // Clip to bilinear support.
        const float inv_cs = 1.0f / cs;
        const float inv_sn = 1.0f / sn;
        float ta = (-LIM - e0) * inv_cs, tb = (LIM - e0) * inv_cs;
        float tc = (-LIM - e1) * inv_sn, td = (LIM - e1) * inv_sn;
        float tlo = fmaxf(fminf(ta, tb), fminf(tc, td));
        float thi = fminf(fmaxf(ta, tb), fmaxf(tc, td));
        float fk0 = fminf(fmaxf(ceilf((tlo - t0v) * inv_dt), 0.0f), 384.0f);
        float fk1 = fminf(fmaxf(floorf((thi - t0v) * inv_dt), -1.0f), 383.0f);
        const int kmin = (int)fk0;
        const int kmax = (int)fk1;
        const int kmid = (kmin + kmax + 1) >> 1;

        // Half lengths; lane runs ceil(max/2) steps at stride 2 (parity split).
        int ldown = kmid - kmin;
        int lup   = kmax - kmid + 1;
        int mylen = (max(max(ldown, lup), 0) + 1) >> 1;
        if (!valid) mylen = 0;

        // Wave envelope (16 adjacent dets x 4 t-phases -> tight).
        int Lw = mylen;
        #pragma unroll
        for (int off = 32; off >= 1; off >>= 1)
            Lw = max(Lw, __shfl_xor(Lw, off, 64));

        const float st0s = st0 * (2.0f * sgn);
        const float st1s = st1 * (2.0f * sgn);
        const int   ks   = h ? (kmid + pp) : (kmid - 1 - pp);
        float i0 = fmaf((float)ks, st0, c0p);
        float i1 = fmaf((float)ks, st1, c1p);
        float acc0 = 0.0f, acc1 = 0.0f, acc2 = 0.0f, acc3 = 0.0f;

        #pragma unroll 4
        for (int m = 0; m < Lw; ++m) {
            // Clamp [0.5,130.49]: identity in-support; overrun -> zero
            // rows/cols for all 4 symmetric reads.
            float q0 = fminf(fmaxf(i0, 0.5f), 130.49f);
            float q1 = fminf(fmaxf(i1, 0.5f), 130.49f);
            i0 += st0s;
            i1 += st1s;
            float f0 = floorf(q0);
            float f1 = floorf(q1);
            float a0 = q0 - f0;
            float a1 = q1 - f1;
            // Byte offsets, float-domain (exact: max 130*532+520 < 2^24).
            float f1b = 4.0f * f1;
            int bidx  = (int)fmaf(f0, 532.0f, f1b);
            int bidx1 = BIDXM - bidx;
            int bidx2 = (int)fmaf(f0, 532.0f, 520.0f - f1b);
            int bidx3 = BIDXM - bidx2;
            unsigned int u0 = *(const unsigned int*)(Pb + bidx);
            unsigned int u1 = *(const unsigned int*)(Pb + bidx + 4);
            unsigned int m0 = *(const unsigned int*)(Pb + bidx1);
            unsigned int m1 = *(const unsigned int*)(Pb + bidx1 + 4);
            unsigned int r0 = *(const unsigned int*)(Pb + bidx2);
            unsigned int r1 = *(const unsigned int*)(Pb + bidx2 + 4);
            unsigned int s0 = *(const unsigned int*)(Pb + bidx3);
            unsigned int s1 = *(const unsigned int*)(Pb + bidx3 + 4);
            half2v w  = __builtin_amdgcn_cvt_pkrtz(1.0f - a0, a0);
            half2v b1 = __builtin_amdgcn_cvt_pkrtz(a1, a1);
            half2v wB = w * b1;                       // v_pk_mul_f16
            half2v wA = w - wB;                       // v_pk_add_f16 (== w*(1-a1))
            unsigned int wAu = __builtin_bit_cast(unsigned int, wA);
            unsigned int wBu = __builtin_bit_cast(unsigned int, wB);
            half2v wmA = __builtin_bit_cast(half2v, __builtin_amdgcn_alignbit(wAu, wAu, 16));
            half2v wmB = __builtin_bit_cast(half2v, __builtin_amdgcn_alignbit(wBu, wBu, 16));
            acc0 = __builtin_amdgcn_fdot2(__builtin_bit_cast(half2v, u0), wA, acc0, false);
            acc0 = __builtin_amdgcn_fdot2(__builtin_bit_cast(half2v, u1), wB, acc0, false);
            acc1 = __builtin_amdgcn_fdot2(__builtin_bit_cast(half2v, m0), wmB, acc1, false);
            acc1 = __builtin_amdgcn_fdot2(__builtin_bit_cast(half2v, m1), wmA, acc1, false);
            acc2 = __builtin_amdgcn_fdot2(__builtin_bit_cast(half2v, r0), wB, acc2, false);
            acc2 = __builtin_amdgcn_fdot2(__builtin_bit_cast(half2v, r1), wA, acc2, false);
            acc3 = __builtin_amdgcn_fdot2(__builtin_bit_cast(half2v, s0), wmA, acc3, false);
            acc3 = __builtin_amdgcn_fdot2(__builtin_bit_cast(half2v, s1), wmB, acc3, false);
        }

        // Combine the 4 t-phase lane groups (same j, ap; different h,p).
        acc0 += __shfl_xor(acc0, 16, 64); acc0 += __shfl_xor(acc0, 32, 64);
        acc1 += __shfl_xor(acc1, 16, 64); acc1 += __shfl_xor(acc1, 32, 64);
        acc2 += __shfl_xor(acc2, 16, 64); acc2 += __shfl_xor(acc2, 32, 64);
        acc3 += __shfl_xor(acc3, 16, 64); acc3 += __shfl_xor(acc3, 32, 64);

        if (valid) {
            float v = (q == 0) ? acc0 : (q == 1) ? acc1 : (q == 2) ? acc2 : acc3;
            int ao  = (q & 2) ? (284 - ap) : ap;
            int det = (q & 1) ? (182 - j) : j;
            // ap==142 / j==91 self-pairs: rewrites with fp-equal values —
            // benign (same as the proven 82us kernel).
            out[img * RAYS + ao * ND + det] = v * (DT_F / 12.0f);
        }
    }
}

extern "C" void kernel_launch(void* const* d_in, const int* in_sizes, int n_in,
                              void* d_out, int out_size, void* d_ws, size_t ws_size,
                              hipStream_t stream) {
    const float* x = (const float*)d_in[0];
    float* out = (float*)d_out;
    const int B = in_sizes[0] / (NI * NI);   // 8
    dim3 grid(B * NBLK);
    radon_fwd<<<grid, TPB, 0, stream>>>(x, out);
}

// Round 4
// 88.994 us; speedup vs baseline: 1.3396x; 1.0643x over previous
//
#include <hip/hip_runtime.h>
#include <stdint.h>

#define NI 128
#define NA 285
#define ND 183
#define NT 384
#define RAYS (NA * ND)        // 52155
#define PITCH 133             // dwords per packed row
#define PROWS 132
#define PLDS (PROWS * PITCH + 1)  // 17557 dwords = 70,228 B -> 2 blocks/CU
#define TPB 832               // 13 waves
#define WAVES 13
#define NBLK 64               // blocks per image -> grid 512 = exactly 2/CU
#define SLOTS (NBLK * WAVES)  // 832 wave slots per image
#define NAP 143               // angle-pair index ap (ap=142 self-pair)
#define NGRPJ 6               // 6 groups of 16 det-pair indices (92 j + 4 pad)
#define NTASKS (NAP * NGRPJ)  // 858 wave-tasks per image
#define ROUNDS 2              // 832*2 = 1664 >= 858; 26 waves run 2 tasks
#define IDXM 17420            // 130*133+130: det-mirror idx' = IDXM - idx
#define BIDXM (IDXM * 4)      // byte-domain mirror constant

typedef __fp16 half2v __attribute__((ext_vector_type(2)));

constexpr float PI_F  = 3.14159265358979323846f;
constexpr float RHO_F = 28.284271247461902f;   // 20*sqrt(2)
constexpr float DX_F  = 0.3125f;
constexpr float DT_F  = 2.0f * RHO_F / NT;

// R18: R17 + tail-free task schedule + med3/unroll micro-trims.
// R17 counters: dur 51us, VALUBusy 41%, DS ~40% (24K base + 25K conflict
// per CU) — neither pipe saturated; the slack is the doubled-wave tail
// (26 of 832 waves ran 2 arbitrary tasks; ~40% of blocks idled 12 waves
// + held LDS while their longest wave drained).
// Fix: exactly 30 tasks are EMPTY — (ap,g=0) where the whole det-group is
// outside the support (20.16*(|c|+|s|) < 23.49 <=> theta<9.45deg or
// >80.55deg <=> ap<=14 or ap>=128). Reorder task IDs so IDs 832..857 (the
// doubled waves' 2nd tasks) are 26 empty tasks (ap in {0..12}u{130..142},
// g=0); the other 832 tasks map 1:1 to waves:
//   t in [0,65):    ap = t/5,        g = 1 + t%5   (ap 0..12)
//   t in [65,767):  ap = 13 + t'/6,  g = t'%6      (ap 13..129, t'=t-65)
//   t in [767,832): ap = 130 + t''/5, g = 1 + t''%5 (ap 130..142, t''=t-767)
// Partition check: 26*5 + 117*6 = 832; + 26 empties = 858 = 143*6. Every
// (ap,g) appears exactly once -> correctness independent of the schedule.
// Micro: fmed3 clamps (-2 VALU/iter), unroll 8.
// Column 1 MUST stay zero (pad col 1 = image col -1): mirror reads at
// col' = 130-f1 hit it for in-support boundary samples (R13's bug).
__global__ __launch_bounds__(TPB) void radon_fwd(const float* __restrict__ x,
                                                 float* __restrict__ out) {
    __shared__ __align__(16) unsigned int P[PLDS];
    const int tid = threadIdx.x;
    const int img = blockIdx.x >> 6;
    const int blk = blockIdx.x & 63;

    // Ring-only zero fill (disjoint from pack writes -> single barrier).
    // rows 0,130,131 full; rows 1..129 cols {0,1,130,131,132}.
    for (int i = tid; i < 1432; i += TPB) {
        int r, c;
        if (i < 399) { r = (i < 133) ? 0 : (i < 266 ? 130 : 131);
                       c = i - ((i < 133) ? 0 : (i < 266 ? 133 : 266)); }
        else { int k = i - 399; r = 1 + (k >> 3);
               const int map[8] = {0, 1, 130, 131, 132, 0, 1, 130};
               c = map[k & 7]; }
        P[r * PITCH + c] = 0;
    }
    if (tid == 0) P[PLDS - 1] = 0;

    // Vertical-pair pack: P[pr*133+pc] = half2(pad[pr][pc], pad[pr+1][pc]),
    // pad = image with 2-cell zero ring. Only pc in [2,129] nonzero.
    const float4* src = (const float4*)(x + img * NI * NI);
    for (int i = tid; i < 129 * 32; i += TPB) {
        int pr  = 1 + (i >> 5);
        int g   = i & 31;
        int rlo = pr - 2;
        int rhi = pr - 1;
        float4 vlo = (rlo >= 0)   ? src[rlo * 32 + g] : make_float4(0, 0, 0, 0);
        float4 vhi = (rhi <= 127) ? src[rhi * 32 + g] : make_float4(0, 0, 0, 0);
        int base = pr * PITCH + 2 + g * 4;
        P[base + 0] = __builtin_bit_cast(unsigned int, __builtin_amdgcn_cvt_pkrtz(vlo.x, vhi.x));
        P[base + 1] = __builtin_bit_cast(unsigned int, __builtin_amdgcn_cvt_pkrtz(vlo.y, vhi.y));
        P[base + 2] = __builtin_bit_cast(unsigned int, __builtin_amdgcn_cvt_pkrtz(vlo.z, vhi.z));
        P[base + 3] = __builtin_bit_cast(unsigned int, __builtin_amdgcn_cvt_pkrtz(vlo.w, vhi.w));
    }
    __syncthreads();

    const int w_id = tid >> 6;
    const int lane = tid & 63;
    const int sidx = blk * WAVES + w_id;        // 0..831
    // x181 mod 832 permutation (gcd=1): scatters tasks across blocks.
    // Doubled waves (perm<26) get 2nd task = 832+perm = an EMPTY task.
    const int perm = (sidx * 181) % SLOTS;
    const int dloc = lane & 15;                 // det-pair within group
    const int q    = lane >> 4;                 // (h,p) t-split
    const int h    = q >> 1;
    const int pp   = q & 1;
    const float sgn = h ? 1.0f : -1.0f;

    const char* Pb = (const char*)P;
    const float inv_dx = 1.0f / DX_F;
    const float inv_dt = 1.0f / DT_F;
    const float t0v    = -RHO_F + 0.5f * DT_F;
    const float LIM    = 20.157f;   // bilinear support |p| <= 20 + DX/2 (+ fp margin)

    for (int r = 0; r < ROUNDS; ++r) {
        const int task = r * SLOTS + perm;      // wave-uniform
        if (task >= NTASKS) break;              // only possible at r==1
        // Task reorder (see header): empties last.
        int ap, g;
        if (task < 65)       { ap = task / 5;              g = 1 + task % 5; }
        else if (task < 767) { int u = task - 65;  ap = 13 + u / 6;  g = u % 6; }
        else if (task < 832) { int u = task - 767; ap = 130 + u / 5; g = 1 + u % 5; }
        else                 { int e = task - 832; ap = (e < 13) ? e : (117 + e); g = 0; }
        const int j  = g * 16 + dloc;           // det-pair index, valid < 92
        const bool valid = (j < 92);

        const float ang = ((float)ap + 0.5f) * (PI_F / (float)NA);
        float sn, cs;
        sincosf(ang, &sn, &cs);
        const float s = -RHO_F + ((float)j + 0.5f) * (2.0f * RHO_F / (float)ND);

        const float e0 = -s * sn;
        const float e1 =  s * cs;
        const float c0p = (e0 + t0v * cs + 20.0f) * inv_dx + 1.5f;  // padded
        const float c1p = (e1 + t0v * sn + 20.0f) * inv_dx + 1.5f;
        const float st0 = DT_F * cs * inv_dx;
        const float st1 = DT_F * sn * inv_dx;

        // Clip to bilinear support.
        const float inv_cs = 1.0f / cs;
        const float inv_sn = 1.0f / sn;
        float ta = (-LIM - e0) * inv_cs, tb = (LIM - e0) * inv_cs;
        float tc = (-LIM - e1) * inv_sn, td = (LIM - e1) * inv_sn;
        float tlo = fmaxf(fminf(ta, tb), fminf(tc, td));
        float thi = fminf(fmaxf(ta, tb), fmaxf(tc, td));
        float fk0 = fminf(fmaxf(ceilf((tlo - t0v) * inv_dt), 0.0f), 384.0f);
        float fk1 = fminf(fmaxf(floorf((thi - t0v) * inv_dt), -1.0f), 383.0f);
        const int kmin = (int)fk0;
        const int kmax = (int)fk1;
        const int kmid = (kmin + kmax + 1) >> 1;

        // Half lengths; lane runs ceil(max/2) steps at stride 2 (parity split).
        int ldown = kmid - kmin;
        int lup   = kmax - kmid + 1;
        int mylen = (max(max(ldown, lup), 0) + 1) >> 1;
        if (!valid) mylen = 0;

        // Wave envelope (16 adjacent dets x 4 t-phases -> tight).
        int Lw = mylen;
        #pragma unroll
        for (int off = 32; off >= 1; off >>= 1)
            Lw = max(Lw, __shfl_xor(Lw, off, 64));

        const float st0s = st0 * (2.0f * sgn);
        const float st1s = st1 * (2.0f * sgn);
        const int   ks   = h ? (kmid + pp) : (kmid - 1 - pp);
        float i0 = fmaf((float)ks, st0, c0p);
        float i1 = fmaf((float)ks, st1, c1p);
        float acc0 = 0.0f, acc1 = 0.0f, acc2 = 0.0f, acc3 = 0.0f;

        #pragma unroll 8
        for (int m = 0; m < Lw; ++m) {
            // Clamp [0.5,130.49] via med3: identity in-support; overrun ->
            // zero rows/cols for all 4 symmetric reads.
            float q0 = __builtin_amdgcn_fmed3f(i0, 0.5f, 130.49f);
            float q1 = __builtin_amdgcn_fmed3f(i1, 0.5f, 130.49f);
            i0 += st0s;
            i1 += st1s;
            float f0 = floorf(q0);
            float f1 = floorf(q1);
            float a0 = q0 - f0;
            float a1 = q1 - f1;
            // Byte offsets, float-domain (exact: max 130*532+520 < 2^24).
            float f1b = 4.0f * f1;
            int bidx  = (int)fmaf(f0, 532.0f, f1b);
            int bidx1 = BIDXM - bidx;
            int bidx2 = (int)fmaf(f0, 532.0f, 520.0f - f1b);
            int bidx3 = BIDXM - bidx2;
            unsigned int u0 = *(const unsigned int*)(Pb + bidx);
            unsigned int u1 = *(const unsigned int*)(Pb + bidx + 4);
            unsigned int m0 = *(const unsigned int*)(Pb + bidx1);
            unsigned int m1 = *(const unsigned int*)(Pb + bidx1 + 4);
            unsigned int r0 = *(const unsigned int*)(Pb + bidx2);
            unsigned int r1 = *(const unsigned int*)(Pb + bidx2 + 4);
            unsigned int s0 = *(const unsigned int*)(Pb + bidx3);
            unsigned int s1 = *(const unsigned int*)(Pb + bidx3 + 4);
            half2v w  = __builtin_amdgcn_cvt_pkrtz(1.0f - a0, a0);
            half2v b1 = __builtin_amdgcn_cvt_pkrtz(a1, a1);
            half2v wB = w * b1;                       // v_pk_mul_f16
            half2v wA = w - wB;                       // v_pk_add_f16 (== w*(1-a1))
            unsigned int wAu = __builtin_bit_cast(unsigned int, wA);
            unsigned int wBu = __builtin_bit_cast(unsigned int, wB);
            half2v wmA = __builtin_bit_cast(half2v, __builtin_amdgcn_alignbit(wAu, wAu, 16));
            half2v wmB = __builtin_bit_cast(half2v, __builtin_amdgcn_alignbit(wBu, wBu, 16));
            acc0 = __builtin_amdgcn_fdot2(__builtin_bit_cast(half2v, u0), wA, acc0, false);
            acc0 = __builtin_amdgcn_fdot2(__builtin_bit_cast(half2v, u1), wB, acc0, false);
            acc1 = __builtin_amdgcn_fdot2(__builtin_bit_cast(half2v, m0), wmB, acc1, false);
            acc1 = __builtin_amdgcn_fdot2(__builtin_bit_cast(half2v, m1), wmA, acc1, false);
            acc2 = __builtin_amdgcn_fdot2(__builtin_bit_cast(half2v, r0), wB, acc2, false);
            acc2 = __builtin_amdgcn_fdot2(__builtin_bit_cast(half2v, r1), wA, acc2, false);
            acc3 = __builtin_amdgcn_fdot2(__builtin_bit_cast(half2v, s0), wmA, acc3, false);
            acc3 = __builtin_amdgcn_fdot2(__builtin_bit_cast(half2v, s1), wmB, acc3, false);
        }

        // Combine the 4 t-phase lane groups (same j, ap; different h,p).
        acc0 += __shfl_xor(acc0, 16, 64); acc0 += __shfl_xor(acc0, 32, 64);
        acc1 += __shfl_xor(acc1, 16, 64); acc1 += __shfl_xor(acc1, 32, 64);
        acc2 += __shfl_xor(acc2, 16, 64); acc2 += __shfl_xor(acc2, 32, 64);
        acc3 += __shfl_xor(acc3, 16, 64); acc3 += __shfl_xor(acc3, 32, 64);

        if (valid) {
            float v = (q == 0) ? acc0 : (q == 1) ? acc1 : (q == 2) ? acc2 : acc3;
            int ao  = (q & 2) ? (284 - ap) : ap;
            int det = (q & 1) ? (182 - j) : j;
            // ap==142 / j==91 self-pairs: rewrites with fp-equal values —
            // benign (same as the proven 82us kernel).
            out[img * RAYS + ao * ND + det] = v * (DT_F / 12.0f);
        }
    }
}

extern "C" void kernel_launch(void* const* d_in, const int* in_sizes, int n_in,
                              void* d_out, int out_size, void* d_ws, size_t ws_size,
                              hipStream_t stream) {
    const float* x = (const float*)d_in[0];
    float* out = (float*)d_out;
    const int B = in_sizes[0] / (NI * NI);   // 8
    dim3 grid(B * NBLK);
    radon_fwd<<<grid, TPB, 0, stream>>>(x, out);
}

// Round 5
// 80.688 us; speedup vs baseline: 1.4775x; 1.1030x over previous
//
#include <hip/hip_runtime.h>
#include <stdint.h>

#define NI 128
#define NA 285
#define ND 183
#define NT 384
#define RAYS (NA * ND)        // 52155
#define PITCH 133             // dwords per packed row
#define PROWS 132
#define PLDS (PROWS * PITCH + 1)  // 17557 dwords = 70,228 B -> 2 blocks/CU
#define TPB 832               // 13 waves; grid 64 blocks/img
#define NTASK 828             // 92 j-values x 9 angle-pair chunks
#define IDXM 17420            // 130*133+130: det-mirror idx' = IDXM - idx
#define BIDXM (IDXM * 4)      // byte-domain mirror constant

typedef __fp16 half2v __attribute__((ext_vector_type(2)));

constexpr float PI_F  = 3.14159265358979323846f;
constexpr float RHO_F = 28.284271247461902f;   // 20*sqrt(2)
constexpr float DX_F  = 0.3125f;
constexpr float DT_F  = 2.0f * RHO_F / NT;

// R19: restore the proven angle-major structure (session-start kernel,
// ~42us kernel-time) + the two micro-ops validated in R18 (fmed3 clamp,
// unroll 8). Post-mortem of the det-major excursion (R16-R18):
//  - conflicts are ~25K cyc/CU (~20%) in BOTH layouts (measured 6.2-6.5M)
//    — each ds_read2 spans 4 incommensurate 16-lane clusters -> quasi-
//    random banks regardless of per-cluster stride regularity;
//  - det-major lost ~5us to envelope looseness: Lw = max over 16
//    consecutive DETECTORS (chord -> 0 across edge groups) vs max over 16
//    adjacent ANGLES at fixed j (±6%) here;
//  - tail/drain is bounded by ~3.6us (97-iter worst wave) — minor.
// Angle-major: wave = (j, 16 angle-pairs) x 4 (h,p) t-phases; 828 tasks
// over 832 slots — natively tail-free. 4-ray symmetry inner loop.
// Column 1 MUST stay zero (pad col 1 = image col -1): mirror reads at
// col' = 130-f1 hit it for in-support boundary samples (R13's bug).
__global__ __launch_bounds__(TPB) void radon_fwd(const float* __restrict__ x,
                                                 float* __restrict__ out) {
    __shared__ __align__(16) unsigned int P[PLDS];
    const int tid   = threadIdx.x;
    const int img   = blockIdx.x >> 6;
    const int chunk = blockIdx.x & 63;

    // Ring-only zero fill (disjoint from pack writes -> single barrier).
    // rows 0,130,131 full; rows 1..129 cols {0,1,130,131,132}.
    for (int i = tid; i < 1432; i += TPB) {
        int r, c;
        if (i < 399) { r = (i < 133) ? 0 : (i < 266 ? 130 : 131);
                       c = i - ((i < 133) ? 0 : (i < 266 ? 133 : 266)); }
        else { int k = i - 399; r = 1 + (k >> 3);
               const int map[8] = {0, 1, 130, 131, 132, 0, 1, 130};
               c = map[k & 7]; }
        P[r * PITCH + c] = 0;
    }
    if (tid == 0) P[PLDS - 1] = 0;

    // Vertical-pair pack: P[pr*133+pc] = half2(pad[pr][pc], pad[pr+1][pc]),
    // pad = image with 2-cell zero ring. Only pc in [2,129] nonzero.
    const float4* src = (const float4*)(x + img * NI * NI);
    for (int i = tid; i < 129 * 32; i += TPB) {
        int pr  = 1 + (i >> 5);
        int g   = i & 31;
        int rlo = pr - 2;
        int rhi = pr - 1;
        float4 vlo = (rlo >= 0)   ? src[rlo * 32 + g] : make_float4(0, 0, 0, 0);
        float4 vhi = (rhi <= 127) ? src[rhi * 32 + g] : make_float4(0, 0, 0, 0);
        int base = pr * PITCH + 2 + g * 4;
        P[base + 0] = __builtin_bit_cast(unsigned int, __builtin_amdgcn_cvt_pkrtz(vlo.x, vhi.x));
        P[base + 1] = __builtin_bit_cast(unsigned int, __builtin_amdgcn_cvt_pkrtz(vlo.y, vhi.y));
        P[base + 2] = __builtin_bit_cast(unsigned int, __builtin_amdgcn_cvt_pkrtz(vlo.z, vhi.z));
        P[base + 3] = __builtin_bit_cast(unsigned int, __builtin_amdgcn_cvt_pkrtz(vlo.w, vhi.w));
    }
    __syncthreads();

    const int w_id = tid >> 6;
    const int lane = tid & 63;
    const int t    = w_id * 64 + chunk;       // j-interleaved task id
    const int j    = t / 9;                   // detector pair index (0..91)
    const int apc  = t - j * 9;               // angle-pair chunk (0..8)
    const int ap   = apc * 16 + (lane >> 2);  // angle 0..142 valid (143=pad)
    const int q    = lane & 3;                // (h,p): h=q>>1, p=q&1
    const bool valid = (t < NTASK) && (ap < 143);

    const float ang = ((float)ap + 0.5f) * (PI_F / (float)NA);
    float sn, cs;
    sincosf(ang, &sn, &cs);
    const float s   = -RHO_F + ((float)j + 0.5f) * (2.0f * RHO_F / (float)ND);
    const float t0v = -RHO_F + 0.5f * DT_F;
    const float inv_dx = 1.0f / DX_F;

    const float e0 = -s * sn;
    const float e1 =  s * cs;
    const float c0p = (e0 + t0v * cs + 20.0f) * inv_dx + 1.5f;  // padded
    const float c1p = (e1 + t0v * sn + 20.0f) * inv_dx + 1.5f;
    const float st0 = DT_F * cs * inv_dx;
    const float st1 = DT_F * sn * inv_dx;

    // Clip to bilinear support |p| <= 20 + DX/2 (+ fp margin).
    const float LIM = 20.157f;
    const float inv_cs = 1.0f / cs;
    const float inv_sn = 1.0f / sn;
    float ta = (-LIM - e0) * inv_cs, tb = (LIM - e0) * inv_cs;
    float tc = (-LIM - e1) * inv_sn, td = (LIM - e1) * inv_sn;
    float tlo = fmaxf(fminf(ta, tb), fminf(tc, td));
    float thi = fminf(fmaxf(ta, tb), fmaxf(tc, td));

    const float inv_dt = 1.0f / DT_F;
    float fk0 = fminf(fmaxf(ceilf((tlo - t0v) * inv_dt), 0.0f), 384.0f);
    float fk1 = fminf(fmaxf(floorf((thi - t0v) * inv_dt), -1.0f), 383.0f);
    const int kmin = (int)fk0;
    const int kmax = (int)fk1;
    const int kmid = (kmin + kmax + 1) >> 1;

    // Half lengths; lane runs ceil(max/2) steps at stride 2 (parity split).
    int ldown = kmid - kmin;
    int lup   = kmax - kmid + 1;
    int mylen = (max(max(ldown, lup), 0) + 1) >> 1;
    if (!valid) mylen = 0;

    // Wave envelope (16 adjacent angle-pairs at fixed j -> tight).
    int Lw = mylen;
    #pragma unroll
    for (int off = 32; off >= 1; off >>= 1)
        Lw = max(Lw, __shfl_xor(Lw, off, 64));

    const int h = q >> 1;
    const int p = q & 1;
    const float sgn  = h ? 1.0f : -1.0f;
    const float st0s = st0 * (2.0f * sgn);
    const float st1s = st1 * (2.0f * sgn);
    const int   ks   = h ? (kmid + p) : (kmid - 1 - p);
    float i0 = fmaf((float)ks, st0, c0p);
    float i1 = fmaf((float)ks, st1, c1p);

    const char* Pb = (const char*)P;
    float acc0 = 0.0f, acc1 = 0.0f, acc2 = 0.0f, acc3 = 0.0f;

    #pragma unroll 8
    for (int m = 0; m < Lw; ++m) {
        // Clamp [0.5,130.49] via med3: identity in-support; overrun ->
        // zero rows/cols for all 4 symmetric reads.
        float q0 = __builtin_amdgcn_fmed3f(i0, 0.5f, 130.49f);
        float q1 = __builtin_amdgcn_fmed3f(i1, 0.5f, 130.49f);
        i0 += st0s;
        i1 += st1s;
        float f0 = floorf(q0);
        float f1 = floorf(q1);
        float a0 = q0 - f0;
        float a1 = q1 - f1;
        // Byte offsets, float-domain (exact: max 130*532+520 = 69680 < 2^24).
        float f1b = 4.0f * f1;
        int bidx  = (int)fmaf(f0, 532.0f, f1b);
        int bidx1 = BIDXM - bidx;
        int bidx2 = (int)fmaf(f0, 532.0f, 520.0f - f1b);
        int bidx3 = BIDXM - bidx2;
        unsigned int u0 = *(const unsigned int*)(Pb + bidx);
        unsigned int u1 = *(const unsigned int*)(Pb + bidx + 4);
        unsigned int m0 = *(const unsigned int*)(Pb + bidx1);
        unsigned int m1 = *(const unsigned int*)(Pb + bidx1 + 4);
        unsigned int r0 = *(const unsigned int*)(Pb + bidx2);
        unsigned int r1 = *(const unsigned int*)(Pb + bidx2 + 4);
        unsigned int s0 = *(const unsigned int*)(Pb + bidx3);
        unsigned int s1 = *(const unsigned int*)(Pb + bidx3 + 4);
        half2v w  = __builtin_amdgcn_cvt_pkrtz(1.0f - a0, a0);
        half2v b1 = __builtin_amdgcn_cvt_pkrtz(a1, a1);
        half2v wB = w * b1;                       // v_pk_mul_f16
        half2v wA = w - wB;                       // v_pk_add_f16 (== w*(1-a1))
        unsigned int wAu = __builtin_bit_cast(unsigned int, wA);
        unsigned int wBu = __builtin_bit_cast(unsigned int, wB);
        half2v wmA = __builtin_bit_cast(half2v, __builtin_amdgcn_alignbit(wAu, wAu, 16));
        half2v wmB = __builtin_bit_cast(half2v, __builtin_amdgcn_alignbit(wBu, wBu, 16));
        acc0 = __builtin_amdgcn_fdot2(__builtin_bit_cast(half2v, u0), wA, acc0, false);
        acc0 = __builtin_amdgcn_fdot2(__builtin_bit_cast(half2v, u1), wB, acc0, false);
        acc1 = __builtin_amdgcn_fdot2(__builtin_bit_cast(half2v, m0), wmB, acc1, false);
        acc1 = __builtin_amdgcn_fdot2(__builtin_bit_cast(half2v, m1), wmA, acc1, false);
        acc2 = __builtin_amdgcn_fdot2(__builtin_bit_cast(half2v, r0), wB, acc2, false);
        acc2 = __builtin_amdgcn_fdot2(__builtin_bit_cast(half2v, r1), wA, acc2, false);
        acc3 = __builtin_amdgcn_fdot2(__builtin_bit_cast(half2v, s0), wmA, acc3, false);
        acc3 = __builtin_amdgcn_fdot2(__builtin_bit_cast(half2v, s1), wmB, acc3, false);
    }

    // Combine the 4-lane group (same j, ap; different h,p subsets).
    acc0 += __shfl_xor(acc0, 1, 64); acc0 += __shfl_xor(acc0, 2, 64);
    acc1 += __shfl_xor(acc1, 1, 64); acc1 += __shfl_xor(acc1, 2, 64);
    acc2 += __shfl_xor(acc2, 1, 64); acc2 += __shfl_xor(acc2, 2, 64);
    acc3 += __shfl_xor(acc3, 1, 64); acc3 += __shfl_xor(acc3, 2, 64);

    if (valid) {
        float v = (q == 0) ? acc0 : (q == 1) ? acc1 : (q == 2) ? acc2 : acc3;
        int ao  = (q & 2) ? (284 - ap) : ap;
        int det = (q & 1) ? (182 - j) : j;
        // ap==142 self-pairs: q2/q3 rewrite q0/q1's outputs with fp-equal
        // values — benign.
        out[img * RAYS + ao * ND + det] = v * (DT_F / 12.0f);
    }
}

extern "C" void kernel_launch(void* const* d_in, const int* in_sizes, int n_in,
                              void* d_out, int out_size, void* d_ws, size_t ws_size,
                              hipStream_t stream) {
    const float* x = (const float*)d_in[0];
    float* out = (float*)d_out;
    const int B = in_sizes[0] / (NI * NI);   // 8
    dim3 grid(B * 64);
    radon_fwd<<<grid, TPB, 0, stream>>>(x, out);
}